// Round 1
// baseline (3589.314 us; speedup 1.0000x reference)
//
#include <hip/hip_runtime.h>
#include <hip/hip_bf16.h>
#include <math.h>

// Problem constants (match reference)
#define Nn 50000
#define Ee 1600000
#define Gg 64
#define HID 64
#define NHEAD 4
#define CHAN 16

__device__ __forceinline__ void atomicMaxFloat(float* addr, float value) {
    if (value >= 0.f)
        atomicMax((int*)addr, __float_as_int(value));
    else
        atomicMin((unsigned int*)addr, __float_as_uint(value));
}

// h = relu(x @ Wn + bn); x: [N,32], Wn: [32,64]
__global__ void k_encode(const float* __restrict__ x, const float* __restrict__ Wn,
                         const float* __restrict__ bn, float* __restrict__ h) {
    __shared__ float sW[32 * 64];
    for (int t = threadIdx.x; t < 32 * 64; t += blockDim.x) sW[t] = Wn[t];
    __syncthreads();
    int lane = threadIdx.x & 63, wv = threadIdx.x >> 6;
    for (int it = 0; it < 16; ++it) {
        int n = blockIdx.x * 64 + it * 4 + wv;
        if (n >= Nn) continue;
        float xv = x[n * 32 + (lane & 31)];
        float acc = bn[lane];
#pragma unroll
        for (int i = 0; i < 32; ++i)
            acc = fmaf(__shfl(xv, i, 32), sW[i * 64 + lane], acc);
        h[n * 64 + lane] = fmaxf(acc, 0.f);
    }
}

// qn/kn/vn = h @ W{q,k,v} + b{q,k,v}
__global__ void k_qkv(const float* __restrict__ h,
                      const float* __restrict__ Wq, const float* __restrict__ bq,
                      const float* __restrict__ Wk, const float* __restrict__ bk,
                      const float* __restrict__ Wv, const float* __restrict__ bv,
                      float* __restrict__ qn, float* __restrict__ kn, float* __restrict__ vn) {
    __shared__ float sq[4096], sk[4096], sv[4096];
    for (int t = threadIdx.x; t < 4096; t += blockDim.x) {
        sq[t] = Wq[t]; sk[t] = Wk[t]; sv[t] = Wv[t];
    }
    __syncthreads();
    int lane = threadIdx.x & 63, wv = threadIdx.x >> 6;
    for (int it = 0; it < 16; ++it) {
        int n = blockIdx.x * 64 + it * 4 + wv;
        if (n >= Nn) continue;
        float hv = h[n * 64 + lane];
        float aq = bq[lane], ak = bk[lane], av = bv[lane];
#pragma unroll
        for (int i = 0; i < 64; ++i) {
            float hi = __shfl(hv, i, 64);
            aq = fmaf(hi, sq[i * 64 + lane], aq);
            ak = fmaf(hi, sk[i * 64 + lane], ak);
            av = fmaf(hi, sv[i * 64 + lane], av);
        }
        qn[n * 64 + lane] = aq;
        kn[n * 64 + lane] = ak;
        vn[n * 64 + lane] = av;
    }
}

__global__ void k_init(float* __restrict__ agg, float* __restrict__ amax,
                       float* __restrict__ denom) {
    int idx = blockIdx.x * blockDim.x + threadIdx.x;
    if (idx < Nn * 64) agg[idx] = 0.f;
    if (idx < Nn * 4) { amax[idx] = -INFINITY; denom[idx] = 0.f; }
}

// Pass A: alpha[e,h] = (q[dst] . (k[src]+e))/sqrt(C); amax[dst,h] = max(alpha)
__global__ void k_edge_a(const float* __restrict__ qn, const float* __restrict__ kn,
                         const int* __restrict__ ei, const float* __restrict__ ea,
                         const float* __restrict__ We, float* __restrict__ alpha,
                         float* __restrict__ amax) {
    __shared__ float sWe[16 * 64];
    for (int t = threadIdx.x; t < 1024; t += blockDim.x) sWe[t] = We[t];
    __syncthreads();
    int lane = threadIdx.x & 63, wv = threadIdx.x >> 6;
    for (int it = 0; it < 16; ++it) {
        int e = blockIdx.x * 64 + it * 4 + wv;
        if (e >= Ee) continue;
        int src = ei[e], dst = ei[Ee + e];
        float av = ea[e * 16 + (lane & 15)];
        float ej = 0.f;
#pragma unroll
        for (int i = 0; i < 16; ++i)
            ej = fmaf(__shfl(av, i, 16), sWe[i * 64 + lane], ej);
        float t = qn[dst * 64 + lane] * (kn[src * 64 + lane] + ej);
#pragma unroll
        for (int off = 8; off >= 1; off >>= 1)
            t += __shfl_down(t, off, 16);
        if ((lane & 15) == 0) {
            float a = t * 0.25f;  // 1/sqrt(16)
            alpha[e * 4 + (lane >> 4)] = a;
            atomicMaxFloat(&amax[dst * 4 + (lane >> 4)], a);
        }
    }
}

// Pass B: ex = exp(alpha - amax[dst]); agg[dst] += (v[src]+e)*ex; denom[dst] += ex
__global__ void k_edge_b(const float* __restrict__ vn, const int* __restrict__ ei,
                         const float* __restrict__ ea, const float* __restrict__ We,
                         const float* __restrict__ alpha, const float* __restrict__ amax,
                         float* __restrict__ agg, float* __restrict__ denom) {
    __shared__ float sWe[16 * 64];
    for (int t = threadIdx.x; t < 1024; t += blockDim.x) sWe[t] = We[t];
    __syncthreads();
    int lane = threadIdx.x & 63, wv = threadIdx.x >> 6;
    for (int it = 0; it < 16; ++it) {
        int e = blockIdx.x * 64 + it * 4 + wv;
        if (e >= Ee) continue;
        int src = ei[e], dst = ei[Ee + e];
        int head = lane >> 4;
        float al = alpha[e * 4 + head];
        float mx = amax[dst * 4 + head];
        float ex = expf(al - mx);
        float av = ea[e * 16 + (lane & 15)];
        float ej = 0.f;
#pragma unroll
        for (int i = 0; i < 16; ++i)
            ej = fmaf(__shfl(av, i, 16), sWe[i * 64 + lane], ej);
        float vj = vn[src * 64 + lane] + ej;
        atomicAdd(&agg[dst * 64 + lane], vj * ex);
        if ((lane & 15) == 0) atomicAdd(&denom[dst * 4 + head], ex);
    }
}

// h += relu(agg/denom + h @ Ws + bs)
__global__ void k_update(float* __restrict__ h, const float* __restrict__ agg,
                         const float* __restrict__ denom, const float* __restrict__ Ws,
                         const float* __restrict__ bs) {
    __shared__ float sW[4096];
    for (int t = threadIdx.x; t < 4096; t += blockDim.x) sW[t] = Ws[t];
    __syncthreads();
    int lane = threadIdx.x & 63, wv = threadIdx.x >> 6;
    for (int it = 0; it < 16; ++it) {
        int n = blockIdx.x * 64 + it * 4 + wv;
        if (n >= Nn) continue;
        float hv = h[n * 64 + lane];
        float sk = bs[lane];
#pragma unroll
        for (int i = 0; i < 64; ++i)
            sk = fmaf(__shfl(hv, i, 64), sW[i * 64 + lane], sk);
        float d = denom[n * 4 + (lane >> 4)];
        float a = agg[n * 64 + lane] / (d + 1e-16f);
        h[n * 64 + lane] = hv + fmaxf(a + sk, 0.f);
    }
}

__global__ void k_pool(const float* __restrict__ h, const int* __restrict__ batch,
                       float* __restrict__ pooled, float* __restrict__ cnt) {
    int idx = blockIdx.x * blockDim.x + threadIdx.x;
    if (idx >= Nn * 64) return;
    int n = idx >> 6, j = idx & 63;
    int g = batch[n];
    atomicAdd(&pooled[g * 64 + j], h[idx]);
    if (j == 0) atomicAdd(&cnt[g], 1.f);
}

// out[g] = relu(pooled/cnt @ W1 + b1) @ W2 + b2
__global__ void k_final(const float* __restrict__ pooled, const float* __restrict__ cnt,
                        const float* __restrict__ W1, const float* __restrict__ b1,
                        const float* __restrict__ W2, const float* __restrict__ b2,
                        float* __restrict__ out) {
    int g = blockIdx.x;
    int t = threadIdx.x;  // 64 threads
    __shared__ float sp[64], sh[32];
    float c = fmaxf(cnt[g], 1.f);
    sp[t] = pooled[g * 64 + t] / c;
    __syncthreads();
    if (t < 32) {
        float acc = b1[t];
#pragma unroll
        for (int i = 0; i < 64; ++i) acc = fmaf(sp[i], W1[i * 32 + t], acc);
        sh[t] = fmaxf(acc, 0.f) * W2[t];
    }
    __syncthreads();
    if (t == 0) {
        float s = b2[0];
#pragma unroll
        for (int i = 0; i < 32; ++i) s += sh[i];
        out[g] = s;
    }
}

extern "C" void kernel_launch(void* const* d_in, const int* in_sizes, int n_in,
                              void* d_out, int out_size, void* d_ws, size_t ws_size,
                              hipStream_t stream) {
    const float* x   = (const float*)d_in[0];
    const int*   ei  = (const int*)d_in[1];
    const float* ea  = (const float*)d_in[2];
    const int*   bat = (const int*)d_in[3];
    const float* Wn  = (const float*)d_in[4];
    const float* bn  = (const float*)d_in[5];
    const float* Wq  = (const float*)d_in[6];
    const float* bq  = (const float*)d_in[7];
    const float* Wk  = (const float*)d_in[8];
    const float* bk  = (const float*)d_in[9];
    const float* Wv  = (const float*)d_in[10];
    const float* bv  = (const float*)d_in[11];
    const float* We  = (const float*)d_in[12];
    const float* Wsk = (const float*)d_in[13];
    const float* bs  = (const float*)d_in[14];
    const float* W1  = (const float*)d_in[15];
    const float* b1  = (const float*)d_in[16];
    const float* W2  = (const float*)d_in[17];
    const float* b2  = (const float*)d_in[18];
    float* out = (float*)d_out;

    float* W = (float*)d_ws;
    const size_t NH = (size_t)Nn * 64;
    float* h      = W;
    float* qn     = W + NH;
    float* kn     = W + 2 * NH;
    float* vn     = W + 3 * NH;
    float* agg    = W + 4 * NH;
    float* alpha  = W + 5 * NH;            // E*4
    float* amax   = alpha + (size_t)Ee * 4;  // N*4
    float* denom  = amax + (size_t)Nn * 4;   // N*4
    float* pooled = denom + (size_t)Nn * 4;  // G*64
    float* cnt    = pooled + Gg * 64;        // G

    dim3 blk(256);
    int nodeBlocks = (Nn + 63) / 64;
    int edgeBlocks = (Ee + 63) / 64;
    int flatBlocks = (Nn * 64 + 255) / 256;

    k_encode<<<nodeBlocks, blk, 0, stream>>>(x, Wn, bn, h);
    for (int l = 0; l < 3; ++l) {
        k_qkv<<<nodeBlocks, blk, 0, stream>>>(h, Wq + l * 4096, bq + l * 64,
                                              Wk + l * 4096, bk + l * 64,
                                              Wv + l * 4096, bv + l * 64, qn, kn, vn);
        k_init<<<flatBlocks, blk, 0, stream>>>(agg, amax, denom);
        k_edge_a<<<edgeBlocks, blk, 0, stream>>>(qn, kn, ei, ea, We + l * 1024, alpha, amax);
        k_edge_b<<<edgeBlocks, blk, 0, stream>>>(vn, ei, ea, We + l * 1024, alpha, amax, agg, denom);
        k_update<<<nodeBlocks, blk, 0, stream>>>(h, agg, denom, Wsk + l * 4096, bs + l * 64);
    }
    hipMemsetAsync(pooled, 0, (Gg * 64 + Gg) * sizeof(float), stream);
    k_pool<<<flatBlocks, blk, 0, stream>>>(h, bat, pooled, cnt);
    k_final<<<Gg, 64, 0, stream>>>(pooled, cnt, W1, b1, W2, b2, out);
}